// Round 1
// baseline (455.583 us; speedup 1.0000x reference)
//
#include <hip/hip_runtime.h>
#include <cstdint>
#include <cstddef>

#define B_TOK 1024
#define DD_IN 3072
#define RHID 128
#define NEXP 8
#define EHID 2048
#define NCLS 10

typedef __attribute__((ext_vector_type(8))) short short8;
typedef __attribute__((ext_vector_type(4))) float floatx4;

// ---- helpers ------------------------------------------------------------
__device__ __forceinline__ unsigned short f2bf(float f) {
  unsigned u = __builtin_bit_cast(unsigned, f);
  u += 0x7fffu + ((u >> 16) & 1u);           // RNE
  return (unsigned short)(u >> 16);
}
__device__ __forceinline__ unsigned pk_bf16(float a, float b) {
  return (unsigned)f2bf(a) | ((unsigned)f2bf(b) << 16);
}
__device__ __forceinline__ float bf2f(unsigned short h) {
  unsigned u = ((unsigned)h) << 16;
  return __builtin_bit_cast(float, u);
}
__device__ __forceinline__ void gload16(const void* g, void* l) {
  __builtin_amdgcn_global_load_lds((const __attribute__((address_space(1))) void*)g,
                                   (__attribute__((address_space(3))) void*)l, 16, 0, 0);
}

// ---- router GEMM1 (fp32, split-K S=16): partial[s][tok][hid] ------------
// Also: emits bf16 copy of x (each x element loaded exactly once here), and
// zeroes cnt[] (block 0,0) so the separate memset dispatch is dropped.
__global__ __launch_bounds__(256) void k_router_gemm(const float* __restrict__ x,
                                                     const float* __restrict__ rW1,
                                                     float* __restrict__ partial,
                                                     unsigned short* __restrict__ xbf,
                                                     int* __restrict__ cnt) {
  if (blockIdx.x == 0 && blockIdx.y == 0 && threadIdx.x < NEXP) cnt[threadIdx.x] = 0;
  const int ttile = blockIdx.x;   // 16 tiles x 64 tokens
  const int s = blockIdx.y;       // 16 K-slices x 192
  const int T0 = ttile * 64;
  const int K0 = s * 192;
  __shared__ float xs[16][64];     // [k][tok]
  __shared__ float wsm[16][132];   // [k][hid], +4 pad
  float acc[4][8];
#pragma unroll
  for (int i = 0; i < 4; i++)
#pragma unroll
    for (int j = 0; j < 8; j++) acc[i][j] = 0.f;
  const int tx = threadIdx.x & 15, ty = threadIdx.x >> 4;
  const int tid = threadIdx.x;

  const int xtok = tid >> 2, xk = (tid & 3) << 2;       // x loader coords
  const int wk0 = tid >> 5, wf0 = (tid & 31) << 2;      // rW1 loader (2 rounds)

  float4 pX, pW0, pW1;
  // prologue: load chunk 0
  pX  = *(const float4*)(x + (size_t)(T0 + xtok) * DD_IN + K0 + xk);
  pW0 = *(const float4*)(rW1 + (size_t)(K0 + wk0) * RHID + wf0);
  pW1 = *(const float4*)(rW1 + (size_t)(K0 + wk0 + 8) * RHID + wf0);

  for (int kc = K0; kc < K0 + 192; kc += 16) {
    // store staged regs -> LDS (transpose x) + emit bf16 x copy
    xs[xk + 0][xtok] = pX.x; xs[xk + 1][xtok] = pX.y;
    xs[xk + 2][xtok] = pX.z; xs[xk + 3][xtok] = pX.w;
    {
      uint2 xw;
      xw.x = pk_bf16(pX.x, pX.y);
      xw.y = pk_bf16(pX.z, pX.w);
      *(uint2*)(xbf + (size_t)(T0 + xtok) * DD_IN + kc + xk) = xw;
    }
    *(float4*)&wsm[wk0][wf0] = pW0;
    *(float4*)&wsm[wk0 + 8][wf0] = pW1;
    __syncthreads();
    if (kc + 16 < K0 + 192) {
      pX  = *(const float4*)(x + (size_t)(T0 + xtok) * DD_IN + kc + 16 + xk);
      pW0 = *(const float4*)(rW1 + (size_t)(kc + 16 + wk0) * RHID + wf0);
      pW1 = *(const float4*)(rW1 + (size_t)(kc + 16 + wk0 + 8) * RHID + wf0);
    }
#pragma unroll
    for (int kk = 0; kk < 16; kk++) {
      float wv[8], xv[4];
      *(float4*)&wv[0] = *(const float4*)&wsm[kk][tx * 8];
      *(float4*)&wv[4] = *(const float4*)&wsm[kk][tx * 8 + 4];
#pragma unroll
      for (int i = 0; i < 4; i++) xv[i] = xs[kk][ty * 4 + i];
#pragma unroll
      for (int i = 0; i < 4; i++)
#pragma unroll
        for (int j = 0; j < 8; j++) acc[i][j] += xv[i] * wv[j];
    }
    __syncthreads();
  }
#pragma unroll
  for (int i = 0; i < 4; i++) {
    float* p = partial + ((size_t)s * B_TOK + T0 + ty * 4 + i) * RHID + tx * 8;
    *(float4*)p = *(float4*)&acc[i][0];
    *(float4*)(p + 4) = *(float4*)&acc[i][4];
  }
}

// ---- router finalize: reduce partials, relu, logits, top-2, bucket build
__global__ __launch_bounds__(256) void k_router_fin(const float* __restrict__ partial,
                                                    const float* __restrict__ rb1,
                                                    const float* __restrict__ rW2,
                                                    const float* __restrict__ rb2,
                                                    const float* __restrict__ eb2,
                                                    float* __restrict__ out,
                                                    int* __restrict__ cnt,
                                                    int* __restrict__ tokL,
                                                    float* __restrict__ wtL) {
  if (threadIdx.x < 4 * NCLS)
    out[blockIdx.x * 4 * NCLS + threadIdx.x] = eb2[threadIdx.x % NCLS];
  const int lane = threadIdx.x & 63;
  const int tok = blockIdx.x * 4 + (threadIdx.x >> 6);
  float r0 = 0.f, r1 = 0.f;
#pragma unroll
  for (int s = 0; s < 16; s++) {
    const float* p = partial + ((size_t)s * B_TOK + tok) * RHID;
    r0 += p[lane]; r1 += p[lane + 64];
  }
  r0 = fmaxf(r0 + rb1[lane], 0.f);
  r1 = fmaxf(r1 + rb1[lane + 64], 0.f);
  float lg[8];
#pragma unroll
  for (int c = 0; c < 8; c++)
    lg[c] = r0 * rW2[lane * 8 + c] + r1 * rW2[(lane + 64) * 8 + c];
#pragma unroll
  for (int off = 32; off >= 1; off >>= 1)
#pragma unroll
    for (int c = 0; c < 8; c++) lg[c] += __shfl_down(lg[c], off);
  if (lane == 0) {
    float m1 = -1e30f, m2 = -1e30f; int i1 = 0, i2 = 0;
#pragma unroll
    for (int c = 0; c < 8; c++) {
      float l = lg[c] + rb2[c];
      if (l > m1) { m2 = m1; i2 = i1; m1 = l; i1 = c; }
      else if (l > m2) { m2 = l; i2 = c; }
    }
    float w1 = 1.f / (1.f + expf(m2 - m1));
    float w2 = 1.f - w1;
    int p1 = atomicAdd(&cnt[i1], 1);
    tokL[i1 * B_TOK + p1] = tok; wtL[i1 * B_TOK + p1] = w1;
    int p2 = atomicAdd(&cnt[i2], 1);
    tokL[i2 * B_TOK + p2] = tok; wtL[i2 * B_TOK + p2] = w2;
  }
}

// ---- expert kernel v2: M=256 token tiles (eW1 read ONCE), 512 threads,
// A: bf16 via global_load_lds (XOR-swizzled source, swizzled ds_read_b128),
// B: fp32 double-register-staged -> bf16 LDS, counted vmcnt(8) pipeline.
#define ISSUE_B(s_) do { _Pragma("unroll") for (int i_ = 0; i_ < 2; i_++) { \
    sBa[s_][i_] = *(const float4*)pB[i_]; \
    sBb[s_][i_] = *(const float4*)(pB[i_] + EHID); \
    pB[i_] += (size_t)64 * EHID; } } while (0)

#define ISSUE_A(p_) do { _Pragma("unroll") for (int i_ = 0; i_ < 4; i_++) { \
    gload16((const void*)srcA[i_], (void*)&u.a.As[p_][i_ * 64 + w8][0]); \
    srcA[i_] += 64; } } while (0)

#define CONV_B(s_) do { _Pragma("unroll") for (int i_ = 0; i_ < 2; i_++) { \
    uint4 wv_; \
    wv_.x = pk_bf16(sBa[s_][i_].x, sBb[s_][i_].x); \
    wv_.y = pk_bf16(sBa[s_][i_].y, sBb[s_][i_].y); \
    wv_.z = pk_bf16(sBa[s_][i_].z, sBb[s_][i_].z); \
    wv_.w = pk_bf16(sBa[s_][i_].w, sBb[s_][i_].w); \
    *(uint4*)&u.a.Bs[bk + i_ * 16][bn4] = wv_; } } while (0)

#define PIPE_SYNC(N_) do { \
    asm volatile("s_waitcnt vmcnt(" #N_ ") lgkmcnt(0)" ::: "memory"); \
    __builtin_amdgcn_sched_barrier(0); \
    __builtin_amdgcn_s_barrier(); \
    __builtin_amdgcn_sched_barrier(0); } while (0)

#define END_BAR do { \
    __builtin_amdgcn_sched_barrier(0); \
    __builtin_amdgcn_s_barrier(); \
    __builtin_amdgcn_sched_barrier(0); } while (0)

#define MFMA_PH(p_) do { \
  _Pragma("unroll") for (int kk = 0; kk < 2; kk++) { \
    short8 af[4], bfr[4]; \
    _Pragma("unroll") for (int mi = 0; mi < 4; mi++) { \
      int row_ = wm + mi * 16 + col; \
      int cs_ = (kk * 4 + quad) ^ (row_ & 7); \
      af[mi] = *(const short8*)((const char*)&u.a.As[p_][0][0] + row_ * 128 + (cs_ << 4)); \
    } \
    _Pragma("unroll") for (int ni = 0; ni < 4; ni++) { \
      int kb_ = kk * 16 + quad * 4, nb_ = wn + ni * 16 + col; \
      uint4 t_; \
      t_.x = u.a.Bs[kb_ + 0][nb_]; t_.y = u.a.Bs[kb_ + 1][nb_]; \
      t_.z = u.a.Bs[kb_ + 2][nb_]; t_.w = u.a.Bs[kb_ + 3][nb_]; \
      bfr[ni] = __builtin_bit_cast(short8, t_); \
    } \
    _Pragma("unroll") for (int mi = 0; mi < 4; mi++) \
      _Pragma("unroll") for (int ni = 0; ni < 4; ni++) \
        acc[mi][ni] = __builtin_amdgcn_mfma_f32_16x16x32_bf16(af[mi], bfr[ni], acc[mi][ni], 0, 0, 0); \
  } } while (0)

__global__ __launch_bounds__(512, 2) void k_expert(const unsigned short* __restrict__ xbf,
                                                   const float* __restrict__ eW1,
                                                   const float* __restrict__ eb1,
                                                   const float* __restrict__ eW2,
                                                   const int* __restrict__ cnt,
                                                   const int* __restrict__ tokL,
                                                   const float* __restrict__ wtL,
                                                   float* __restrict__ out) {
  const int nt = blockIdx.x;
  // ---- scheduler: tile id -> (e, mt); tiles are 256 tokens now
  int mt = blockIdx.y;
  int e = 0;
#pragma unroll
  for (e = 0; e < NEXP; e++) {
    int te = (cnt[e] + 255) >> 8;
    if (mt < te) break;
    mt -= te;
  }
  if (e >= NEXP) return;
  const int cnt_e = cnt[e];

  __shared__ union {
    struct { unsigned short As[2][256][64]; unsigned Bs[32][132]; } a; // 65536+16896
    struct { unsigned short ehs[256][132]; float w2[128 * NCLS]; } b;  // 67584+5120
  } u;
  __shared__ int stok[256];
  __shared__ float swt[256];

  const int tid = threadIdx.x;
  if (tid < 256) {
    int r = mt * 256 + tid;
    bool v = r < cnt_e;
    stok[tid] = v ? tokL[e * B_TOK + r] : -1;
    swt[tid]  = v ? wtL[e * B_TOK + r] : 0.f;
  }
  __syncthreads();   // stok visible before A-pointer setup

  const int lane = tid & 63;
  const int wv = tid >> 6;
  const int w8 = wv << 3;                              // wave-uniform LDS row base
  const int wm = (wv >> 1) * 64, wn = (wv & 1) * 64;   // wave 64x64 subtile (4M x 2N)
  const int col = lane & 15, quad = lane >> 4;

  floatx4 acc[4][4];
#pragma unroll
  for (int mi = 0; mi < 4; mi++)
#pragma unroll
    for (int ni = 0; ni < 4; ni++) acc[mi][ni] = (floatx4)0.f;

  // ---- A source pointers (gathered bf16 rows; XOR-pre-swizzled column)
  const int r8 = tid >> 3, c16 = tid & 7;
  const int c16s = c16 ^ (r8 & 7);   // (row & 7) is i-invariant since 64 % 8 == 0
  const unsigned short* srcA[4];
#pragma unroll
  for (int i = 0; i < 4; i++) {
    int tk = stok[r8 + i * 64];
    if (tk < 0) tk = 0;              // invalid rows read token 0; output masked later
    srcA[i] = xbf + (size_t)tk * DD_IN + (c16s << 3);
  }
  // ---- B pointers (fp32 eW1 row pairs)
  const float* W1e = eW1 + (size_t)e * DD_IN * EHID + (size_t)nt * 128;
  const int bk = tid >> 5, bn4 = (tid & 31) << 2;
  const float* pB[2];
#pragma unroll
  for (int i = 0; i < 2; i++) pB[i] = W1e + (size_t)(2 * (bk + i * 16)) * EHID + bn4;

  float4 sBa[2][2], sBb[2][2];

  // ---- prologue: chunk 0 in flight
  ISSUE_B(0);
  ISSUE_A(0);

  // ---- main loop: 48 K-chunks of 64, 2 per iteration, vmcnt(8) steady state
  for (int t = 0; t < 48; t += 2) {
    // even chunk t (parity 0)
    ISSUE_B(1); ISSUE_A(1);          // chunk t+1
    CONV_B(0);                       // compiler auto-waits exactly B(t)'s loads
    PIPE_SYNC(8);                    // A(t) landed; 8 ops (B,A of t+1) stay in flight
    MFMA_PH(0);
    END_BAR;
    // odd chunk t+1 (parity 1)
    if (t < 46) {
      ISSUE_B(0); ISSUE_A(0);        // chunk t+2
      CONV_B(1);
      PIPE_SYNC(8);
    } else {
      CONV_B(1);
      PIPE_SYNC(0);                  // final drain
    }
    MFMA_PH(1);
    END_BAR;
  }

  // ---- epilogue: +eb1, relu, store eh (bf16) to LDS
#pragma unroll
  for (int ni = 0; ni < 4; ni++) {
    int hid = wn + ni * 16 + col;
    float bias = eb1[(size_t)e * EHID + nt * 128 + hid];
#pragma unroll
    for (int mi = 0; mi < 4; mi++)
#pragma unroll
      for (int r = 0; r < 4; r++) {
        float val = fmaxf(acc[mi][ni][r] + bias, 0.f);
        u.b.ehs[wm + mi * 16 + quad * 4 + r][hid] = f2bf(val);
      }
  }
  // stage eW2 chunk (128 x 10)
#pragma unroll
  for (int i = 0; i < 3; i++) {
    int idx = tid + i * 512;
    if (idx < 128 * NCLS)
      u.b.w2[idx] = eW2[((size_t)e * EHID + nt * 128 + idx / NCLS) * NCLS + (idx % NCLS)];
  }
  __syncthreads();
  // layer2 partial: each thread handles (token, half of 128 hid)
  {
    int tok = tid >> 1, half = tid & 1;
    float a10[NCLS];
#pragma unroll
    for (int c = 0; c < NCLS; c++) a10[c] = 0.f;
    for (int hh = 0; hh < 64; hh++) {
      int h = half * 64 + hh;
      float eh = bf2f(u.b.ehs[tok][h]);
#pragma unroll
      for (int c = 0; c < NCLS; c++) a10[c] += eh * u.b.w2[h * NCLS + c];
    }
    int tk = stok[tok];
    if (tk >= 0) {
      float wt = swt[tok];
#pragma unroll
      for (int c = 0; c < NCLS; c++)
        atomicAdd(out + (size_t)tk * NCLS + c, wt * a10[c]);
    }
  }
}

// ---- launch -------------------------------------------------------------
extern "C" void kernel_launch(void* const* d_in, const int* in_sizes, int n_in,
                              void* d_out, int out_size, void* d_ws, size_t ws_size,
                              hipStream_t stream) {
  const float* x   = (const float*)d_in[0];
  const float* rW1 = (const float*)d_in[1];
  const float* rb1 = (const float*)d_in[2];
  const float* rW2 = (const float*)d_in[3];
  const float* rb2 = (const float*)d_in[4];
  const float* eW1 = (const float*)d_in[5];
  const float* eb1 = (const float*)d_in[6];
  const float* eW2 = (const float*)d_in[7];
  const float* eb2 = (const float*)d_in[8];
  float* out = (float*)d_out;

  char* ws = (char*)d_ws;
  int*   cnt     = (int*)(ws + 0);         // 8 ints (zeroed by k_router_gemm)
  int*   tokL    = (int*)(ws + 1024);      // 8*1024 int
  float* wtL     = (float*)(ws + 33792);   // 8*1024 float
  float* partial = (float*)(ws + 66560);   // 16*1024*128 float = 8 MB
  unsigned short* xbf = (unsigned short*)(ws + 66560 + (size_t)16 * B_TOK * RHID * 4); // 6.3 MB

  k_router_gemm<<<dim3(16, 16), 256, 0, stream>>>(x, rW1, partial, xbf, cnt);
  k_router_fin<<<256, 256, 0, stream>>>(partial, rb1, rW2, rb2, eb2, out, cnt, tokL, wtL);
  k_expert<<<dim3(16, 16), 512, 0, stream>>>(xbf, eW1, eb1, eW2, cnt, tokL, wtL, out);
}

// Round 2
// 423.255 us; speedup vs baseline: 1.0764x; 1.0764x over previous
//
#include <hip/hip_runtime.h>
#include <cstdint>
#include <cstddef>

#define B_TOK 1024
#define DD_IN 3072
#define RHID 128
#define NEXP 8
#define EHID 2048
#define NCLS 10

typedef __attribute__((ext_vector_type(8))) short short8;
typedef __attribute__((ext_vector_type(4))) float floatx4;

// ---- helpers ------------------------------------------------------------
__device__ __forceinline__ unsigned short f2bf(float f) {
  unsigned u = __builtin_bit_cast(unsigned, f);
  u += 0x7fffu + ((u >> 16) & 1u);           // RNE
  return (unsigned short)(u >> 16);
}
__device__ __forceinline__ unsigned pk_bf16(float a, float b) {
  return (unsigned)f2bf(a) | ((unsigned)f2bf(b) << 16);
}
__device__ __forceinline__ float bf2f(unsigned short h) {
  unsigned u = ((unsigned)h) << 16;
  return __builtin_bit_cast(float, u);
}
__device__ __forceinline__ void gload16(const void* g, void* l) {
  __builtin_amdgcn_global_load_lds((const __attribute__((address_space(1))) void*)g,
                                   (__attribute__((address_space(3))) void*)l, 16, 0, 0);
}

// ---- router GEMM1 (fp32, split-K S=16): partial[s][tok][hid] ------------
// Also emits bf16 copy of x (each x element loaded exactly once here), and
// zeroes cnt[] (block 0,0).
__global__ __launch_bounds__(256) void k_router_gemm(const float* __restrict__ x,
                                                     const float* __restrict__ rW1,
                                                     float* __restrict__ partial,
                                                     unsigned short* __restrict__ xbf,
                                                     int* __restrict__ cnt) {
  if (blockIdx.x == 0 && blockIdx.y == 0 && threadIdx.x < NEXP) cnt[threadIdx.x] = 0;
  const int ttile = blockIdx.x;   // 16 tiles x 64 tokens
  const int s = blockIdx.y;       // 16 K-slices x 192
  const int T0 = ttile * 64;
  const int K0 = s * 192;
  __shared__ float xs[16][64];     // [k][tok]
  __shared__ float wsm[16][132];   // [k][hid], +4 pad
  float acc[4][8];
#pragma unroll
  for (int i = 0; i < 4; i++)
#pragma unroll
    for (int j = 0; j < 8; j++) acc[i][j] = 0.f;
  const int tx = threadIdx.x & 15, ty = threadIdx.x >> 4;
  const int tid = threadIdx.x;

  const int xtok = tid >> 2, xk = (tid & 3) << 2;       // x loader coords
  const int wk0 = tid >> 5, wf0 = (tid & 31) << 2;      // rW1 loader (2 rounds)

  float4 pX, pW0, pW1;
  pX  = *(const float4*)(x + (size_t)(T0 + xtok) * DD_IN + K0 + xk);
  pW0 = *(const float4*)(rW1 + (size_t)(K0 + wk0) * RHID + wf0);
  pW1 = *(const float4*)(rW1 + (size_t)(K0 + wk0 + 8) * RHID + wf0);

  for (int kc = K0; kc < K0 + 192; kc += 16) {
    xs[xk + 0][xtok] = pX.x; xs[xk + 1][xtok] = pX.y;
    xs[xk + 2][xtok] = pX.z; xs[xk + 3][xtok] = pX.w;
    {
      uint2 xw;
      xw.x = pk_bf16(pX.x, pX.y);
      xw.y = pk_bf16(pX.z, pX.w);
      *(uint2*)(xbf + (size_t)(T0 + xtok) * DD_IN + kc + xk) = xw;
    }
    *(float4*)&wsm[wk0][wf0] = pW0;
    *(float4*)&wsm[wk0 + 8][wf0] = pW1;
    __syncthreads();
    if (kc + 16 < K0 + 192) {
      pX  = *(const float4*)(x + (size_t)(T0 + xtok) * DD_IN + kc + 16 + xk);
      pW0 = *(const float4*)(rW1 + (size_t)(kc + 16 + wk0) * RHID + wf0);
      pW1 = *(const float4*)(rW1 + (size_t)(kc + 16 + wk0 + 8) * RHID + wf0);
    }
#pragma unroll
    for (int kk = 0; kk < 16; kk++) {
      float wv[8], xv[4];
      *(float4*)&wv[0] = *(const float4*)&wsm[kk][tx * 8];
      *(float4*)&wv[4] = *(const float4*)&wsm[kk][tx * 8 + 4];
#pragma unroll
      for (int i = 0; i < 4; i++) xv[i] = xs[kk][ty * 4 + i];
#pragma unroll
      for (int i = 0; i < 4; i++)
#pragma unroll
        for (int j = 0; j < 8; j++) acc[i][j] += xv[i] * wv[j];
    }
    __syncthreads();
  }
#pragma unroll
  for (int i = 0; i < 4; i++) {
    float* p = partial + ((size_t)s * B_TOK + T0 + ty * 4 + i) * RHID + tx * 8;
    *(float4*)p = *(float4*)&acc[i][0];
    *(float4*)(p + 4) = *(float4*)&acc[i][4];
  }
}

// ---- router finalize: reduce partials, relu, logits, top-2, bucket build
__global__ __launch_bounds__(256) void k_router_fin(const float* __restrict__ partial,
                                                    const float* __restrict__ rb1,
                                                    const float* __restrict__ rW2,
                                                    const float* __restrict__ rb2,
                                                    const float* __restrict__ eb2,
                                                    float* __restrict__ out,
                                                    int* __restrict__ cnt,
                                                    int* __restrict__ tokL,
                                                    float* __restrict__ wtL) {
  if (threadIdx.x < 4 * NCLS)
    out[blockIdx.x * 4 * NCLS + threadIdx.x] = eb2[threadIdx.x % NCLS];
  const int lane = threadIdx.x & 63;
  const int tok = blockIdx.x * 4 + (threadIdx.x >> 6);
  float r0 = 0.f, r1 = 0.f;
#pragma unroll
  for (int s = 0; s < 16; s++) {
    const float* p = partial + ((size_t)s * B_TOK + tok) * RHID;
    r0 += p[lane]; r1 += p[lane + 64];
  }
  r0 = fmaxf(r0 + rb1[lane], 0.f);
  r1 = fmaxf(r1 + rb1[lane + 64], 0.f);
  float lg[8];
#pragma unroll
  for (int c = 0; c < 8; c++)
    lg[c] = r0 * rW2[lane * 8 + c] + r1 * rW2[(lane + 64) * 8 + c];
#pragma unroll
  for (int off = 32; off >= 1; off >>= 1)
#pragma unroll
    for (int c = 0; c < 8; c++) lg[c] += __shfl_down(lg[c], off);
  if (lane == 0) {
    float m1 = -1e30f, m2 = -1e30f; int i1 = 0, i2 = 0;
#pragma unroll
    for (int c = 0; c < 8; c++) {
      float l = lg[c] + rb2[c];
      if (l > m1) { m2 = m1; i2 = i1; m1 = l; i1 = c; }
      else if (l > m2) { m2 = l; i2 = c; }
    }
    float w1 = 1.f / (1.f + expf(m2 - m1));
    float w2 = 1.f - w1;
    int p1 = atomicAdd(&cnt[i1], 1);
    tokL[i1 * B_TOK + p1] = tok; wtL[i1 * B_TOK + p1] = w1;
    int p2 = atomicAdd(&cnt[i2], 1);
    tokL[i2 * B_TOK + p2] = tok; wtL[i2 * B_TOK + p2] = w2;
  }
}

// ---- expert kernel v3: M=128 x N=64 tiles, 256 threads, 3 blocks/CU.
// ~640 active blocks -> 2-3 independent 4-wave blocks per CU overlap the
// per-chunk stage/vmcnt/barrier cost that bound v1/v2.
// A: bf16 via global_load_lds (pre-swizzled source + XOR'd ds_read_b128),
// B: fp32 double-register-staged -> swizzled bf16 LDS, vmcnt(8) steady state.
#define ISSUE_B(s_) do { _Pragma("unroll") for (int i_ = 0; i_ < 2; i_++) { \
    sBa[s_][i_] = *(const float4*)pB[i_]; \
    sBb[s_][i_] = *(const float4*)(pB[i_] + EHID); \
    pB[i_] += (size_t)64 * EHID; } } while (0)

#define ISSUE_A(p_) do { _Pragma("unroll") for (int i_ = 0; i_ < 4; i_++) { \
    gload16((const void*)srcA[i_], (void*)&u.a.As[p_][i_ * 32 + w8][0]); \
    srcA[i_] += 64; } } while (0)

#define CONV_B(s_) do { _Pragma("unroll") for (int i_ = 0; i_ < 2; i_++) { \
    uint4 wv_; \
    wv_.x = pk_bf16(sBa[s_][i_].x, sBb[s_][i_].x); \
    wv_.y = pk_bf16(sBa[s_][i_].y, sBb[s_][i_].y); \
    wv_.z = pk_bf16(sBa[s_][i_].z, sBb[s_][i_].z); \
    wv_.w = pk_bf16(sBa[s_][i_].w, sBb[s_][i_].w); \
    int br_ = brow + i_ * 16; \
    *(uint4*)&u.a.Bs[br_][bcol ^ (((br_ >> 2) & 1) << 4)] = wv_; } } while (0)

#define PIPE_SYNC(N_) do { \
    asm volatile("s_waitcnt vmcnt(" #N_ ") lgkmcnt(0)" ::: "memory"); \
    __builtin_amdgcn_sched_barrier(0); \
    __builtin_amdgcn_s_barrier(); \
    __builtin_amdgcn_sched_barrier(0); } while (0)

#define END_BAR do { \
    __builtin_amdgcn_sched_barrier(0); \
    __builtin_amdgcn_s_barrier(); \
    __builtin_amdgcn_sched_barrier(0); } while (0)

#define MFMA_PH(p_) do { \
  _Pragma("unroll") for (int kk = 0; kk < 2; kk++) { \
    short8 af[4], bfr[2]; \
    _Pragma("unroll") for (int mi = 0; mi < 4; mi++) { \
      int row_ = wm + mi * 16 + col; \
      int cs_ = (kk * 4 + quad) ^ (row_ & 7); \
      af[mi] = *(const short8*)((const char*)&u.a.As[p_][0][0] + row_ * 128 + (cs_ << 4)); \
    } \
    _Pragma("unroll") for (int ni = 0; ni < 2; ni++) { \
      int kb_ = kk * 16 + quad * 4; \
      int nb_ = (wn + ni * 16 + col) ^ ((quad & 1) << 4); \
      uint4 t_; \
      t_.x = u.a.Bs[kb_ + 0][nb_]; t_.y = u.a.Bs[kb_ + 1][nb_]; \
      t_.z = u.a.Bs[kb_ + 2][nb_]; t_.w = u.a.Bs[kb_ + 3][nb_]; \
      bfr[ni] = __builtin_bit_cast(short8, t_); \
    } \
    _Pragma("unroll") for (int mi = 0; mi < 4; mi++) \
      _Pragma("unroll") for (int ni = 0; ni < 2; ni++) \
        acc[mi][ni] = __builtin_amdgcn_mfma_f32_16x16x32_bf16(af[mi], bfr[ni], acc[mi][ni], 0, 0, 0); \
  } } while (0)

__global__ __launch_bounds__(256, 3) void k_expert(const unsigned short* __restrict__ xbf,
                                                   const float* __restrict__ eW1,
                                                   const float* __restrict__ eb1,
                                                   const float* __restrict__ eW2,
                                                   const int* __restrict__ cnt,
                                                   const int* __restrict__ tokL,
                                                   const float* __restrict__ wtL,
                                                   float* __restrict__ out) {
  const int nt = blockIdx.x;      // 32 x 64-wide hid slices
  int mt = blockIdx.y;            // token tile (128 rows) via prefix walk
  int e = 0;
#pragma unroll
  for (e = 0; e < NEXP; e++) {
    int te = (cnt[e] + 127) >> 7;
    if (mt < te) break;
    mt -= te;
  }
  if (e >= NEXP) return;
  const int cnt_e = cnt[e];

  __shared__ union {
    struct { unsigned short As[2][128][64]; unsigned Bs[32][64]; } a; // 32768+8192
    struct { unsigned short ehs[128][68]; float w2[64 * NCLS]; } b;   // 17408+2560
  } u;
  __shared__ int stok[128];
  __shared__ float swt[128];

  const int tid = threadIdx.x;
  if (tid < 128) {
    int r = mt * 128 + tid;
    bool v = r < cnt_e;
    stok[tid] = v ? tokL[e * B_TOK + r] : -1;
    swt[tid]  = v ? wtL[e * B_TOK + r] : 0.f;
  }
  __syncthreads();   // stok visible before A-pointer setup

  const int lane = tid & 63;
  const int wv = tid >> 6;                             // 4 waves
  const int w8 = wv << 3;                              // wave-uniform LDS row base
  const int wm = (wv >> 1) << 6, wn = (wv & 1) << 5;   // wave 64x32 subtile
  const int col = lane & 15, quad = lane >> 4;

  floatx4 acc[4][2];
#pragma unroll
  for (int mi = 0; mi < 4; mi++)
#pragma unroll
    for (int ni = 0; ni < 2; ni++) acc[mi][ni] = (floatx4)0.f;

  // ---- A source pointers (gathered bf16 rows; XOR-pre-swizzled column)
  const int r8 = tid >> 3, c16 = tid & 7;
  const int c16s = c16 ^ (r8 & 7);   // (row & 7) is i-invariant since 32 % 8 == 0
  const unsigned short* srcA[4];
#pragma unroll
  for (int i = 0; i < 4; i++) {
    int tk = stok[r8 + i * 32];
    if (tk < 0) tk = 0;              // invalid rows read token 0; output masked later
    srcA[i] = xbf + (size_t)tk * DD_IN + (c16s << 3);
  }
  // ---- B pointers (fp32 eW1 row pairs)
  const float* W1e = eW1 + (size_t)e * DD_IN * EHID + (size_t)nt * 64;
  const int brow = tid >> 4, bcol = (tid & 15) << 2;
  const float* pB[2];
#pragma unroll
  for (int i = 0; i < 2; i++) pB[i] = W1e + (size_t)(2 * (brow + i * 16)) * EHID + bcol;

  float4 sBa[2][2], sBb[2][2];

  // ---- prologue: chunk 0 in flight
  ISSUE_B(0);
  ISSUE_A(0);

  // ---- main loop: 48 K-chunks of 64, 2 per iteration, vmcnt(8) steady state
  for (int t = 0; t < 48; t += 2) {
    // even chunk t (parity 0)
    ISSUE_B(1); ISSUE_A(1);          // chunk t+1
    CONV_B(0);                       // compiler auto-waits exactly B(t)'s loads
    PIPE_SYNC(8);                    // A(t) landed; 8 ops (B,A of t+1) stay in flight
    MFMA_PH(0);
    END_BAR;
    // odd chunk t+1 (parity 1)
    if (t < 46) {
      ISSUE_B(0); ISSUE_A(0);        // chunk t+2
      CONV_B(1);
      PIPE_SYNC(8);
    } else {
      CONV_B(1);
      PIPE_SYNC(0);                  // final drain
    }
    MFMA_PH(1);
    END_BAR;
  }

  // ---- epilogue: +eb1, relu, store eh (bf16) to LDS
#pragma unroll
  for (int ni = 0; ni < 2; ni++) {
    int hid = wn + ni * 16 + col;
    float bias = eb1[(size_t)e * EHID + nt * 64 + hid];
#pragma unroll
    for (int mi = 0; mi < 4; mi++)
#pragma unroll
      for (int r = 0; r < 4; r++) {
        float val = fmaxf(acc[mi][ni][r] + bias, 0.f);
        u.b.ehs[wm + mi * 16 + quad * 4 + r][hid] = f2bf(val);
      }
  }
  // stage eW2 chunk (64 x 10)
#pragma unroll
  for (int i = 0; i < 3; i++) {
    int idx = tid + i * 256;
    if (idx < 64 * NCLS)
      u.b.w2[idx] = eW2[((size_t)e * EHID + nt * 64 + idx / NCLS) * NCLS + (idx % NCLS)];
  }
  __syncthreads();
  // layer2 partial: (token, half of 64 hid) per thread; pair-combine via shfl
  {
    int tok = tid >> 1, half = tid & 1;
    float a10[NCLS];
#pragma unroll
    for (int c = 0; c < NCLS; c++) a10[c] = 0.f;
    for (int hh = 0; hh < 32; hh++) {
      int h = half * 32 + hh;
      float eh = bf2f(u.b.ehs[tok][h]);
#pragma unroll
      for (int c = 0; c < NCLS; c++) a10[c] += eh * u.b.w2[h * NCLS + c];
    }
#pragma unroll
    for (int c = 0; c < NCLS; c++) a10[c] += __shfl_xor(a10[c], 1);
    int tk = stok[tok];
    if (half == 0 && tk >= 0) {
      float wt = swt[tok];
#pragma unroll
      for (int c = 0; c < NCLS; c++)
        atomicAdd(out + (size_t)tk * NCLS + c, wt * a10[c]);
    }
  }
}

// ---- launch -------------------------------------------------------------
extern "C" void kernel_launch(void* const* d_in, const int* in_sizes, int n_in,
                              void* d_out, int out_size, void* d_ws, size_t ws_size,
                              hipStream_t stream) {
  const float* x   = (const float*)d_in[0];
  const float* rW1 = (const float*)d_in[1];
  const float* rb1 = (const float*)d_in[2];
  const float* rW2 = (const float*)d_in[3];
  const float* rb2 = (const float*)d_in[4];
  const float* eW1 = (const float*)d_in[5];
  const float* eb1 = (const float*)d_in[6];
  const float* eW2 = (const float*)d_in[7];
  const float* eb2 = (const float*)d_in[8];
  float* out = (float*)d_out;

  char* ws = (char*)d_ws;
  int*   cnt     = (int*)(ws + 0);         // 8 ints (zeroed by k_router_gemm)
  int*   tokL    = (int*)(ws + 1024);      // 8*1024 int
  float* wtL     = (float*)(ws + 33792);   // 8*1024 float
  float* partial = (float*)(ws + 66560);   // 16*1024*128 float = 8 MB
  unsigned short* xbf = (unsigned short*)(ws + 66560 + (size_t)16 * B_TOK * RHID * 4); // 6.3 MB

  k_router_gemm<<<dim3(16, 16), 256, 0, stream>>>(x, rW1, partial, xbf, cnt);
  k_router_fin<<<256, 256, 0, stream>>>(partial, rb1, rW2, rb2, eb2, out, cnt, tokL, wtL);
  k_expert<<<dim3(32, 24), 256, 0, stream>>>(xbf, eW1, eb1, eW2, cnt, tokL, wtL, out);
}